// Round 2
// baseline (863.758 us; speedup 1.0000x reference)
//
#include <hip/hip_runtime.h>

typedef unsigned short u16;
typedef __attribute__((ext_vector_type(8))) short short8;
typedef __attribute__((ext_vector_type(8))) unsigned short u16x8;
typedef __attribute__((ext_vector_type(4))) float f32x4;

#define NBATCH 2
#define SEQ    4096
#define DIM    2048
#define NHEAD  16
#define HD     128
#define CH     64
#define NC     64           /* SEQ / CH */
#define MROWS  8192         /* NBATCH * SEQ */

__device__ __forceinline__ float b2f(u16 u) {
    unsigned x = ((unsigned)u) << 16;
    return __builtin_bit_cast(float, x);
}
__device__ __forceinline__ u16 f2b(float f) {
    unsigned u = __builtin_bit_cast(unsigned, f);
    u += 0x7fffu + ((u >> 16) & 1u);
    return (u16)(u >> 16);
}

__device__ __forceinline__ void gload_lds16(const u16* g, u16* l) {
    __builtin_amdgcn_global_load_lds(
        (const __attribute__((address_space(1))) void*)g,
        (__attribute__((address_space(3))) void*)l, 16, 0, 0);
}

// ---------------------------------------------------------------------------
// f32 -> bf16 cast (8 elements/thread). n8 = element count / 8.
// ---------------------------------------------------------------------------
__global__ __launch_bounds__(256) void cast_f32_bf16(
    const float* __restrict__ in, u16* __restrict__ out, long n8)
{
    long i = (long)blockIdx.x * 256 + threadIdx.x;
    if (i >= n8) return;
    f32x4 a = ((const f32x4*)in)[2 * i];
    f32x4 b = ((const f32x4*)in)[2 * i + 1];
    u16x8 o;
#pragma unroll
    for (int j = 0; j < 4; j++) { o[j] = f2b(a[j]); o[4 + j] = f2b(b[j]); }
    ((u16x8*)out)[i] = o;
}

// ---------------------------------------------------------------------------
// GEMM: C[m,n] = scale * sum_k A[m,k] * B[n,k]   (both K-major, bf16 in)
// 128x128 tile, BK=32, 256 threads = 4 waves (2x2 of 64x64), mfma 16x16x32.
// LDS kblk XOR-swizzle: data for kblk lives in slot (kblk ^ (row&3)).
// OutT = u16 (bf16) or float.
// ---------------------------------------------------------------------------
#define BM 128
#define BN 128
#define BK 32

template <typename OutT>
__global__ __launch_bounds__(256) void gemm_bt(
    const u16* __restrict__ A, const u16* __restrict__ Bw, OutT* __restrict__ C,
    int M, int N, int K, float scale)
{
    __shared__ __align__(16) u16 As[BM * BK];
    __shared__ __align__(16) u16 Bs[BN * BK];

    const int tid  = threadIdx.x;
    const int wave = tid >> 6, lane = tid & 63;
    const int wr = wave >> 1, wc = wave & 1;
    const int m16 = lane & 15, quad = lane >> 4;
    const long row0 = (long)blockIdx.x * BM;
    const long col0 = (long)blockIdx.y * BN;

    // staging: 512 16B segments per tile; segment idx -> row=idx>>2, slot=idx&3
    const int idx0 = wave * 64 + lane;   // [0,256)
    const int idx1 = idx0 + 256;         // [256,512)
    const int r0 = idx0 >> 2, k0 = ((idx0 & 3) ^ (r0 & 3)) * 8;  // XOR swizzle
    const int r1 = idx1 >> 2, k1 = ((idx1 & 3) ^ (r1 & 3)) * 8;

    const u16* Ab = A  + row0 * K;
    const u16* Bb = Bw + col0 * K;

    f32x4 acc[4][4];
#pragma unroll
    for (int i = 0; i < 4; i++)
#pragma unroll
        for (int j = 0; j < 4; j++) {
            f32x4 z = {0.f, 0.f, 0.f, 0.f};
            acc[i][j] = z;
        }

    // fragment-read slot (loop invariant): slot = quad ^ (row&3), row&3 == m16&3
    const int fslot = (quad ^ (m16 & 3)) * 8;

    for (int kt = 0; kt < K; kt += BK) {
        if (kt) __syncthreads();
        gload_lds16(Ab + (long)r0 * K + kt + k0, &As[idx0 * 8]);
        gload_lds16(Ab + (long)r1 * K + kt + k1, &As[idx1 * 8]);
        gload_lds16(Bb + (long)r0 * K + kt + k0, &Bs[idx0 * 8]);
        gload_lds16(Bb + (long)r1 * K + kt + k1, &Bs[idx1 * 8]);
        __syncthreads();

        short8 af[4], bf[4];
#pragma unroll
        for (int t = 0; t < 4; t++)
            af[t] = *(const short8*)&As[(wr * 64 + t * 16 + m16) * BK + fslot];
#pragma unroll
        for (int t = 0; t < 4; t++)
            bf[t] = *(const short8*)&Bs[(wc * 64 + t * 16 + m16) * BK + fslot];
#pragma unroll
        for (int i = 0; i < 4; i++)
#pragma unroll
            for (int j = 0; j < 4; j++)
                acc[i][j] = __builtin_amdgcn_mfma_f32_16x16x32_bf16(
                    af[i], bf[j], acc[i][j], 0, 0, 0);
    }

    // epilogue: C/D layout col=lane&15 (N), row=quad*4+reg (M)
#pragma unroll
    for (int i = 0; i < 4; i++) {
        const long grow0 = row0 + wr * 64 + i * 16 + quad * 4;
#pragma unroll
        for (int j = 0; j < 4; j++) {
            const long gcol = col0 + wc * 64 + j * 16 + m16;
#pragma unroll
            for (int r = 0; r < 4; r++) {
                float val = acc[i][j][r] * scale;
                if constexpr (sizeof(OutT) == 4)
                    C[(grow0 + r) * N + gcol] = val;
                else
                    C[(grow0 + r) * N + gcol] = f2b(val);
            }
        }
    }
}

// ---------------------------------------------------------------------------
// Pass A: kv[b,h,c][d][e] = sum_t k[t][d] * v[t][e]  (per 64-token chunk)
// grid = B*H*NC blocks, 256 threads; thread computes an 8x8 output block.
// ---------------------------------------------------------------------------
__global__ __launch_bounds__(256) void chunk_kv(
    const u16* __restrict__ Kg, const u16* __restrict__ Vg, u16* __restrict__ KV)
{
    __shared__ float ks[CH * HD];   // 32 KB
    __shared__ float vs[CH * HD];   // 32 KB
    const int tid = threadIdx.x;
    const int blk = blockIdx.x;
    const int c = blk & (NC - 1);
    const int bh = blk >> 6;
    const int h = bh & (NHEAD - 1);
    const int b = bh >> 4;
    const long rowbase = (long)b * SEQ + (long)c * CH;
    const u16* kg = Kg + rowbase * DIM + h * HD;
    const u16* vg = Vg + rowbase * DIM + h * HD;

#pragma unroll
    for (int i = 0; i < 4; i++) {
        int e = (i * 256 + tid) * 8;
        int t = e >> 7, col = e & 127;
        u16x8 a  = *(const u16x8*)(kg + (long)t * DIM + col);
        u16x8 bb = *(const u16x8*)(vg + (long)t * DIM + col);
#pragma unroll
        for (int j = 0; j < 8; j++) {
            ks[t * HD + col + j] = b2f(a[j]);
            vs[t * HD + col + j] = b2f(bb[j]);
        }
    }
    __syncthreads();

    const int dblk = (tid >> 4) * 8, eblk = (tid & 15) * 8;
    float acc[8][8];
#pragma unroll
    for (int i = 0; i < 8; i++)
#pragma unroll
        for (int j = 0; j < 8; j++) acc[i][j] = 0.f;

    for (int t = 0; t < CH; t++) {
        float kf[8], vf[8];
#pragma unroll
        for (int j = 0; j < 8; j++) {
            kf[j] = ks[t * HD + dblk + j];
            vf[j] = vs[t * HD + eblk + j];
        }
#pragma unroll
        for (int a2 = 0; a2 < 8; a2++)
#pragma unroll
            for (int e2 = 0; e2 < 8; e2++) acc[a2][e2] += kf[a2] * vf[e2];
    }

    u16* outp = KV + (long)blk * (HD * HD);
#pragma unroll
    for (int a2 = 0; a2 < 8; a2++) {
        u16x8 p;
#pragma unroll
        for (int e2 = 0; e2 < 8; e2++) p[e2] = f2b(acc[a2][e2]);
        *(u16x8*)(outp + (dblk + a2) * HD + eblk) = p;
    }
}

// ---------------------------------------------------------------------------
// Pass B: in-place exclusive prefix over chunks. Thread owns one (d,e) of the
// 128x128 state for one (b,h); reads kv_c, writes S_c (state BEFORE adding).
// ---------------------------------------------------------------------------
__global__ __launch_bounds__(256) void kv_prefix(u16* __restrict__ KV)
{
    const int bh  = blockIdx.x >> 6;
    const int sub = blockIdx.x & 63;
    const long base = (long)bh * NC * (HD * HD) + sub * 256 + threadIdx.x;
    float s = 0.f;
#pragma unroll 4
    for (int c = 0; c < NC; c++) {
        long a = base + (long)c * (HD * HD);
        float val = b2f(KV[a]);
        KV[a] = f2b(s);
        s += val;
    }
}

// ---------------------------------------------------------------------------
// Pass C: o = mask(q k^T) v + q S_c  per chunk. 512 threads.
// LDS: q bf16 16KB | k bf16 16KB (reused as attn f32 16KB) | v f32 32KB.
// S streamed from global (L1-broadcast across the 64 threads sharing e-range).
// ---------------------------------------------------------------------------
__global__ __launch_bounds__(512) void chunk_out(
    const u16* __restrict__ Q, const u16* __restrict__ Kg,
    const u16* __restrict__ Vg, const u16* __restrict__ Sb, u16* __restrict__ O)
{
    __shared__ __align__(16) u16 qs[CH * HD];    // 16 KB
    __shared__ __align__(16) u16 ksl[CH * HD];   // 16 KB, reused as f32 attn
    __shared__ __align__(16) float vs[CH * HD];  // 32 KB
    const int tid = threadIdx.x;
    const int blk = blockIdx.x;
    const int c = blk & (NC - 1);
    const int bh = blk >> 6;
    const int h = bh & (NHEAD - 1);
    const int b = bh >> 4;
    const long rowbase = (long)b * SEQ + (long)c * CH;
    const u16* qg = Q  + rowbase * DIM + h * HD;
    const u16* kg = Kg + rowbase * DIM + h * HD;
    const u16* vg = Vg + rowbase * DIM + h * HD;

#pragma unroll
    for (int i = 0; i < 2; i++) {
        int e = (i * 512 + tid) * 8;
        int t = e >> 7, col = e & 127;
        *(u16x8*)&qs[e]  = *(const u16x8*)(qg + (long)t * DIM + col);
        *(u16x8*)&ksl[e] = *(const u16x8*)(kg + (long)t * DIM + col);
        u16x8 uv = *(const u16x8*)(vg + (long)t * DIM + col);
#pragma unroll
        for (int j = 0; j < 8; j++) vs[e + j] = b2f(uv[j]);
    }
    __syncthreads();

    // step 1: attn[i][j] = q[i].k[j], causal mask j<=i (q pre-scaled in GEMM)
    const int i = tid >> 3;
    const int j0 = (tid & 7) * 8;
    float a8[8];
#pragma unroll
    for (int jj = 0; jj < 8; jj++) a8[jj] = 0.f;

    for (int d0 = 0; d0 < HD; d0 += 8) {
        float qf[8];
        u16x8 uq = *(const u16x8*)&qs[i * HD + d0];
#pragma unroll
        for (int j = 0; j < 8; j++) qf[j] = b2f(uq[j]);
#pragma unroll
        for (int jj = 0; jj < 8; jj++) {
            u16x8 uk = *(const u16x8*)&ksl[(j0 + jj) * HD + d0];
#pragma unroll
            for (int dd = 0; dd < 8; dd++) a8[jj] += qf[dd] * b2f(uk[dd]);
        }
    }
#pragma unroll
    for (int jj = 0; jj < 8; jj++)
        if (j0 + jj > i) a8[jj] = 0.f;

    __syncthreads();                      // everyone done reading k-tile
    float* attn = (float*)ksl;
#pragma unroll
    for (int jj = 0; jj < 8; jj++) attn[i * CH + j0 + jj] = a8[jj];
    __syncthreads();

    // step 2: o[i][e0..e0+15] = sum_j attn[i][j] v[j][e] + sum_d q[i][d] S[d][e]
    const int e0 = (tid & 7) * 16;
    float acc[16];
#pragma unroll
    for (int e = 0; e < 16; e++) acc[e] = 0.f;

    for (int j = 0; j < CH; j++) {
        float a = attn[i * CH + j];
#pragma unroll
        for (int e = 0; e < 16; e++) acc[e] += a * vs[j * HD + e0 + e];
    }

    const u16* Sg = Sb + (long)blk * (HD * HD);
    for (int d = 0; d < HD; d++) {
        float qv = b2f(qs[i * HD + d]);
        u16x8 s0 = *(const u16x8*)(Sg + d * HD + e0);
        u16x8 s1 = *(const u16x8*)(Sg + d * HD + e0 + 8);
#pragma unroll
        for (int e = 0; e < 8; e++) {
            acc[e]     += qv * b2f(s0[e]);
            acc[8 + e] += qv * b2f(s1[e]);
        }
    }

    u16* og = O + (rowbase + i) * DIM + h * HD + e0;
    u16x8 p0, p1;
#pragma unroll
    for (int e = 0; e < 8; e++) { p0[e] = f2b(acc[e]); p1[e] = f2b(acc[8 + e]); }
    *(u16x8*)og       = p0;
    *(u16x8*)(og + 8) = p1;
}

// ---------------------------------------------------------------------------
extern "C" void kernel_launch(void* const* d_in, const int* in_sizes, int n_in,
                              void* d_out, int out_size, void* d_ws, size_t ws_size,
                              hipStream_t stream)
{
    (void)in_sizes; (void)n_in; (void)out_size; (void)ws_size;
    const float* x  = (const float*)d_in[0];
    const float* Wq = (const float*)d_in[1];
    const float* Wk = (const float*)d_in[2];
    const float* Wv = (const float*)d_in[3];
    const float* Wo = (const float*)d_in[4];
    float* out = (float*)d_out;

    const long NE = (long)MROWS * DIM;        // 16,777,216 elements
    const long WE = (long)DIM * DIM;          //  4,194,304 elements
    u16* xb  = (u16*)d_ws;                    // 33.5 MB
    u16* Wqb = xb  + NE;                      //  8.4 MB each
    u16* Wkb = Wqb + WE;
    u16* Wvb = Wkb + WE;
    u16* Wob = Wvb + WE;
    u16* q   = Wob + WE;                      // 33.5 MB each
    u16* k   = q + NE;
    u16* v   = k + NE;
    u16* kv  = v + NE;                        // 33,554,432 elems = 67.1 MB
    u16* o   = xb;                            // alias: xb dead after proj GEMMs
    // total ws: ~235 MB

    hipLaunchKernelGGL(cast_f32_bf16, dim3(8192), dim3(256), 0, stream, x,  xb,  NE / 8);
    hipLaunchKernelGGL(cast_f32_bf16, dim3(2048), dim3(256), 0, stream, Wq, Wqb, WE / 8);
    hipLaunchKernelGGL(cast_f32_bf16, dim3(2048), dim3(256), 0, stream, Wk, Wkb, WE / 8);
    hipLaunchKernelGGL(cast_f32_bf16, dim3(2048), dim3(256), 0, stream, Wv, Wvb, WE / 8);
    hipLaunchKernelGGL(cast_f32_bf16, dim3(2048), dim3(256), 0, stream, Wo, Wob, WE / 8);

    dim3 ggrid(MROWS / BM, DIM / BN);
    const float qscale = 0.08838834764831845f;  // HD^-0.5

    hipLaunchKernelGGL(gemm_bt<u16>, ggrid, dim3(256), 0, stream, xb, Wqb, q, MROWS, DIM, DIM, qscale);
    hipLaunchKernelGGL(gemm_bt<u16>, ggrid, dim3(256), 0, stream, xb, Wkb, k, MROWS, DIM, DIM, 1.0f);
    hipLaunchKernelGGL(gemm_bt<u16>, ggrid, dim3(256), 0, stream, xb, Wvb, v, MROWS, DIM, DIM, 1.0f);

    hipLaunchKernelGGL(chunk_kv,  dim3(NBATCH * NHEAD * NC), dim3(256), 0, stream, k, v, kv);
    hipLaunchKernelGGL(kv_prefix, dim3(NBATCH * NHEAD * NC), dim3(256), 0, stream, kv);
    hipLaunchKernelGGL(chunk_out, dim3(NBATCH * NHEAD * NC), dim3(512), 0, stream, q, k, v, kv, o);

    hipLaunchKernelGGL(gemm_bt<float>, ggrid, dim3(256), 0, stream, o, Wob, out, MROWS, DIM, DIM, 1.0f);
}

// Round 3
// 698.316 us; speedup vs baseline: 1.2369x; 1.2369x over previous
//
#include <hip/hip_runtime.h>

typedef unsigned short u16;
typedef __attribute__((ext_vector_type(8))) short short8;
typedef __attribute__((ext_vector_type(8))) unsigned short u16x8;
typedef __attribute__((ext_vector_type(4))) unsigned short u16x4;
typedef __attribute__((ext_vector_type(4))) float f32x4;

#define NBATCH 2
#define SEQ    4096
#define DIM    2048
#define NHEAD  16
#define HD     128
#define CH     64
#define NC     64           /* SEQ / CH */
#define MROWS  8192         /* NBATCH * SEQ */

__device__ __forceinline__ float b2f(u16 u) {
    unsigned x = ((unsigned)u) << 16;
    return __builtin_bit_cast(float, x);
}
__device__ __forceinline__ u16 f2b(float f) {
    unsigned u = __builtin_bit_cast(unsigned, f);
    u += 0x7fffu + ((u >> 16) & 1u);
    return (u16)(u >> 16);
}

__device__ __forceinline__ void gload_lds16(const u16* g, u16* l) {
    __builtin_amdgcn_global_load_lds(
        (const __attribute__((address_space(1))) void*)g,
        (__attribute__((address_space(3))) void*)l, 16, 0, 0);
}

// ---------------------------------------------------------------------------
// f32 -> bf16 cast (8 elements/thread). n8 = element count / 8.
// ---------------------------------------------------------------------------
__global__ __launch_bounds__(256) void cast_f32_bf16(
    const float* __restrict__ in, u16* __restrict__ out, long n8)
{
    long i = (long)blockIdx.x * 256 + threadIdx.x;
    if (i >= n8) return;
    f32x4 a = ((const f32x4*)in)[2 * i];
    f32x4 b = ((const f32x4*)in)[2 * i + 1];
    u16x8 o;
#pragma unroll
    for (int j = 0; j < 4; j++) { o[j] = f2b(a[j]); o[4 + j] = f2b(b[j]); }
    ((u16x8*)out)[i] = o;
}

// ---------------------------------------------------------------------------
// GEMM: C[m,n] = scale * sum_k A[m,k] * B[n,k]   (both K-major, bf16 in)
// 128x128 tile, BK=32, 256 threads = 4 waves (2x2 of 64x64), mfma 16x16x32.
// WN: write normal layout Cn[m][n] (OutT = u16 bf16 or float).
// WT: write transposed per-head layout Ct[(b*DIM + n)*SEQ + (m%SEQ)]
//     (i.e. [b,h,hd_col][token], token-contiguous) as packed 8B stores.
// ---------------------------------------------------------------------------
#define BM 128
#define BN 128
#define BK 32

template <bool WN, bool WT, typename OutT>
__global__ __launch_bounds__(256) void gemm_bt(
    const u16* __restrict__ A, const u16* __restrict__ Bw,
    OutT* __restrict__ Cn, u16* __restrict__ Ct,
    int M, int N, int K, float scale)
{
    __shared__ __align__(16) u16 As[BM * BK];
    __shared__ __align__(16) u16 Bs[BN * BK];

    const int tid  = threadIdx.x;
    const int wave = tid >> 6, lane = tid & 63;
    const int wr = wave >> 1, wc = wave & 1;
    const int m16 = lane & 15, quad = lane >> 4;
    const long row0 = (long)blockIdx.x * BM;
    const long col0 = (long)blockIdx.y * BN;

    const int idx0 = wave * 64 + lane;   // [0,256)
    const int idx1 = idx0 + 256;         // [256,512)
    const int r0 = idx0 >> 2, k0 = ((idx0 & 3) ^ (r0 & 3)) * 8;  // XOR swizzle
    const int r1 = idx1 >> 2, k1 = ((idx1 & 3) ^ (r1 & 3)) * 8;

    const u16* Ab = A  + row0 * K;
    const u16* Bb = Bw + col0 * K;

    f32x4 acc[4][4];
#pragma unroll
    for (int i = 0; i < 4; i++)
#pragma unroll
        for (int j = 0; j < 4; j++) {
            f32x4 z = {0.f, 0.f, 0.f, 0.f};
            acc[i][j] = z;
        }

    const int fslot = (quad ^ (m16 & 3)) * 8;

    for (int kt = 0; kt < K; kt += BK) {
        if (kt) __syncthreads();
        gload_lds16(Ab + (long)r0 * K + kt + k0, &As[idx0 * 8]);
        gload_lds16(Ab + (long)r1 * K + kt + k1, &As[idx1 * 8]);
        gload_lds16(Bb + (long)r0 * K + kt + k0, &Bs[idx0 * 8]);
        gload_lds16(Bb + (long)r1 * K + kt + k1, &Bs[idx1 * 8]);
        __syncthreads();

        short8 af[4], bf[4];
#pragma unroll
        for (int t = 0; t < 4; t++)
            af[t] = *(const short8*)&As[(wr * 64 + t * 16 + m16) * BK + fslot];
#pragma unroll
        for (int t = 0; t < 4; t++)
            bf[t] = *(const short8*)&Bs[(wc * 64 + t * 16 + m16) * BK + fslot];
#pragma unroll
        for (int i = 0; i < 4; i++)
#pragma unroll
            for (int j = 0; j < 4; j++)
                acc[i][j] = __builtin_amdgcn_mfma_f32_16x16x32_bf16(
                    af[i], bf[j], acc[i][j], 0, 0, 0);
    }

    // epilogue: C/D layout col=lane&15 (N), row=quad*4+reg (M)
#pragma unroll
    for (int i = 0; i < 4; i++) {
        const long grow0 = row0 + wr * 64 + i * 16 + quad * 4;
#pragma unroll
        for (int j = 0; j < 4; j++) {
            const long gcol = col0 + wc * 64 + j * 16 + m16;
            if constexpr (WN) {
#pragma unroll
                for (int r = 0; r < 4; r++) {
                    float val = acc[i][j][r] * scale;
                    if constexpr (sizeof(OutT) == 4)
                        Cn[(grow0 + r) * N + gcol] = val;
                    else
                        Cn[(grow0 + r) * N + gcol] = f2b(val);
                }
            }
            if constexpr (WT) {
                u16x4 p;
#pragma unroll
                for (int r = 0; r < 4; r++) p[r] = f2b(acc[i][j][r] * scale);
                const long b = grow0 >> 12;           // batch (SEQ=4096 rows)
                const long t0 = grow0 & (SEQ - 1);
                *(u16x4*)(Ct + (b * DIM + gcol) * SEQ + t0) = p;
            }
        }
    }
}

// ---------------------------------------------------------------------------
// chunk_kv (MFMA): kvT[blk][e][d] = sum_t V[t][e] K[t][d]
//   = sum_t Vt[e][t] Kt[d][t] : A-op = Vt rows, B-op = Kt rows (t-contig).
// 2048 blocks x 256 thr (4 waves 2x2 of 64x64). No LDS: frags from global.
// ---------------------------------------------------------------------------
__global__ __launch_bounds__(256) void chunk_kv_mfma(
    const u16* __restrict__ Vt, const u16* __restrict__ Kt, u16* __restrict__ KV)
{
    const int tid = threadIdx.x, blk = blockIdx.x;
    const int c = blk & (NC - 1), bh = blk >> 6;
    const int wave = tid >> 6, lane = tid & 63;
    const int wr = wave >> 1, wc = wave & 1;
    const int m16 = lane & 15, quad = lane >> 4;
    const u16* vb = Vt + (long)bh * HD * SEQ + c * CH;
    const u16* kb = Kt + (long)bh * HD * SEQ + c * CH;

    f32x4 acc[4][4];
#pragma unroll
    for (int i = 0; i < 4; i++)
#pragma unroll
        for (int j = 0; j < 4; j++) {
            f32x4 z = {0.f, 0.f, 0.f, 0.f};
            acc[i][j] = z;
        }

#pragma unroll
    for (int tk = 0; tk < 2; tk++) {
        short8 af[4], bf[4];
#pragma unroll
        for (int t = 0; t < 4; t++)
            af[t] = *(const short8*)(vb + (long)(wr * 64 + t * 16 + m16) * SEQ + tk * 32 + quad * 8);
#pragma unroll
        for (int t = 0; t < 4; t++)
            bf[t] = *(const short8*)(kb + (long)(wc * 64 + t * 16 + m16) * SEQ + tk * 32 + quad * 8);
#pragma unroll
        for (int i = 0; i < 4; i++)
#pragma unroll
            for (int j = 0; j < 4; j++)
                acc[i][j] = __builtin_amdgcn_mfma_f32_16x16x32_bf16(
                    af[i], bf[j], acc[i][j], 0, 0, 0);
    }

    u16* outp = KV + (long)blk * (HD * HD);
#pragma unroll
    for (int i = 0; i < 4; i++)
#pragma unroll
        for (int j = 0; j < 4; j++)
#pragma unroll
            for (int r = 0; r < 4; r++)
                outp[(wr * 64 + i * 16 + quad * 4 + r) * HD + wc * 64 + j * 16 + m16]
                    = f2b(acc[i][j][r]);
}

// ---------------------------------------------------------------------------
// exclusive prefix over chunks, in place on kvT (layout-agnostic elementwise).
// ---------------------------------------------------------------------------
__global__ __launch_bounds__(256) void kv_prefix(u16* __restrict__ KV)
{
    const int bh  = blockIdx.x >> 6;
    const int sub = blockIdx.x & 63;
    const long base = (long)bh * NC * (HD * HD) + sub * 256 + threadIdx.x;
    float s = 0.f;
#pragma unroll 4
    for (int c = 0; c < NC; c++) {
        long a = base + (long)c * (HD * HD);
        float val = b2f(KV[a]);
        KV[a] = f2b(s);
        s += val;
    }
}

// ---------------------------------------------------------------------------
// chunk_out (MFMA): O = mask(Q K^T) V + Q S  per 64-token chunk.
// 2048 blocks x 256 thr; wave w owns m-tile w (16 rows), full e-range.
// Only LDS: 9 KB attn-matrix buffer (C-layout -> A-layout round trip).
// All operand fragments read directly from global (all contraction-contig):
//   Q[m][d] (q), K[j][d] (k), S^T[e][d] (kvT), V^T[e][t] (vt).
// ---------------------------------------------------------------------------
#define AMP 72   /* padded LDS stride: 36 dwords == 4 mod 32 -> conflict-free */

__global__ __launch_bounds__(256) void chunk_out_mfma(
    const u16* __restrict__ Q, const u16* __restrict__ Kn,
    const u16* __restrict__ Vt, const u16* __restrict__ Sb, u16* __restrict__ O)
{
    __shared__ __align__(16) u16 Am[CH * AMP];   // 9216 B, masked attn bf16

    const int tid = threadIdx.x, blk = blockIdx.x;
    const int c = blk & (NC - 1), bh = blk >> 6;
    const int h = bh & (NHEAD - 1), b = bh >> 4;
    const long rowbase = (long)b * SEQ + (long)c * CH;
    const int wave = tid >> 6, lane = tid & 63;   // wave = m-tile
    const int m16 = lane & 15, quad = lane >> 4;

    const u16* qrow = Q  + (rowbase + wave * 16 + m16) * DIM + h * HD;
    const u16* krow = Kn + rowbase * DIM + h * HD;

    // Q A-fragments, shared by QK^T and Q*S (both contract over d)
    short8 qa[4];
#pragma unroll
    for (int dk = 0; dk < 4; dk++)
        qa[dk] = *(const short8*)(qrow + dk * 32 + quad * 8);

    // ---- phase 1: A = Q K^T (64x64), causal mask, -> LDS in A-op layout ----
    f32x4 acc1[4];
#pragma unroll
    for (int jt = 0; jt < 4; jt++) {
        f32x4 z = {0.f, 0.f, 0.f, 0.f};
        acc1[jt] = z;
    }
#pragma unroll
    for (int dk = 0; dk < 4; dk++)
#pragma unroll
        for (int jt = 0; jt < 4; jt++) {
            short8 bb = *(const short8*)(krow + (long)(jt * 16 + m16) * DIM + dk * 32 + quad * 8);
            acc1[jt] = __builtin_amdgcn_mfma_f32_16x16x32_bf16(qa[dk], bb, acc1[jt], 0, 0, 0);
        }
    const int mbase = wave * 16 + quad * 4;
#pragma unroll
    for (int jt = 0; jt < 4; jt++) {
        const int j = jt * 16 + m16;
#pragma unroll
        for (int r = 0; r < 4; r++) {
            float v = (j <= mbase + r) ? acc1[jt][r] : 0.f;
            Am[(mbase + r) * AMP + j] = f2b(v);
        }
    }

    // ---- phase 2: acc = Q * S  (S^T rows from kvT, d-contiguous) ----
    f32x4 acc[8];
#pragma unroll
    for (int et = 0; et < 8; et++) {
        f32x4 z = {0.f, 0.f, 0.f, 0.f};
        acc[et] = z;
    }
    const u16* Sg = Sb + (long)blk * (HD * HD);
#pragma unroll
    for (int dk = 0; dk < 4; dk++)
#pragma unroll
        for (int et = 0; et < 8; et++) {
            short8 sb = *(const short8*)(Sg + (et * 16 + m16) * HD + dk * 32 + quad * 8);
            acc[et] = __builtin_amdgcn_mfma_f32_16x16x32_bf16(qa[dk], sb, acc[et], 0, 0, 0);
        }

    // ---- phase 3: acc += A * V  (A from LDS, V^T rows t-contiguous) ----
    // wave wrote & reads only its own 16 Am rows: lgkmcnt ordering suffices.
    const u16* vb = Vt + (long)bh * HD * SEQ + c * CH;
#pragma unroll
    for (int tk = 0; tk < 2; tk++) {
        short8 a = *(const short8*)&Am[(wave * 16 + m16) * AMP + tk * 32 + quad * 8];
#pragma unroll
        for (int et = 0; et < 8; et++) {
            short8 vbf = *(const short8*)(vb + (long)(et * 16 + m16) * SEQ + tk * 32 + quad * 8);
            acc[et] = __builtin_amdgcn_mfma_f32_16x16x32_bf16(a, vbf, acc[et], 0, 0, 0);
        }
    }

    // ---- epilogue ----
#pragma unroll
    for (int et = 0; et < 8; et++) {
        const int e = et * 16 + m16;
#pragma unroll
        for (int r = 0; r < 4; r++) {
            const int m = wave * 16 + quad * 4 + r;
            O[(rowbase + m) * DIM + h * HD + e] = f2b(acc[et][r]);
        }
    }
}

// ---------------------------------------------------------------------------
extern "C" void kernel_launch(void* const* d_in, const int* in_sizes, int n_in,
                              void* d_out, int out_size, void* d_ws, size_t ws_size,
                              hipStream_t stream)
{
    (void)in_sizes; (void)n_in; (void)out_size; (void)ws_size;
    const float* x  = (const float*)d_in[0];
    const float* Wq = (const float*)d_in[1];
    const float* Wk = (const float*)d_in[2];
    const float* Wv = (const float*)d_in[3];
    const float* Wo = (const float*)d_in[4];
    float* out = (float*)d_out;

    const long NE = (long)MROWS * DIM;        // 16,777,216 elements
    const long WE = (long)DIM * DIM;          //  4,194,304 elements
    u16* xb  = (u16*)d_ws;                    // 33.5 MB
    u16* Wqb = xb  + NE;
    u16* Wkb = Wqb + WE;
    u16* Wvb = Wkb + WE;
    u16* Wob = Wvb + WE;
    u16* q   = Wob + WE;                      // 33.5 MB each
    u16* k   = q + NE;
    u16* vt  = k + NE;                        // transposed [b,h,e][t]
    u16* kv  = vt + NE;                       // 67.1 MB (kvT per chunk)
    u16* o   = xb;                            // alias: xb dead after projections
    u16* kt  = (u16*)d_out;                   // scratch in d_out (overwritten by final GEMM)
    // ws total: 6*NE + 4*WE elems = ~235 MB (same footprint as round 2)

    hipLaunchKernelGGL(cast_f32_bf16, dim3(8192), dim3(256), 0, stream, x,  xb,  NE / 8);
    hipLaunchKernelGGL(cast_f32_bf16, dim3(2048), dim3(256), 0, stream, Wq, Wqb, WE / 8);
    hipLaunchKernelGGL(cast_f32_bf16, dim3(2048), dim3(256), 0, stream, Wk, Wkb, WE / 8);
    hipLaunchKernelGGL(cast_f32_bf16, dim3(2048), dim3(256), 0, stream, Wv, Wvb, WE / 8);
    hipLaunchKernelGGL(cast_f32_bf16, dim3(2048), dim3(256), 0, stream, Wo, Wob, WE / 8);

    dim3 ggrid(MROWS / BM, DIM / BN);
    const float qscale = 0.08838834764831845f;  // HD^-0.5

    hipLaunchKernelGGL((gemm_bt<true,  false, u16>),  ggrid, dim3(256), 0, stream,
                       xb, Wqb, q, (u16*)nullptr, MROWS, DIM, DIM, qscale);
    hipLaunchKernelGGL((gemm_bt<true,  true,  u16>),  ggrid, dim3(256), 0, stream,
                       xb, Wkb, k, kt, MROWS, DIM, DIM, 1.0f);
    hipLaunchKernelGGL((gemm_bt<false, true,  u16>),  ggrid, dim3(256), 0, stream,
                       xb, Wvb, (u16*)nullptr, vt, MROWS, DIM, DIM, 1.0f);

    hipLaunchKernelGGL(chunk_kv_mfma, dim3(NBATCH * NHEAD * NC), dim3(256), 0, stream, vt, kt, kv);
    hipLaunchKernelGGL(kv_prefix,     dim3(NBATCH * NHEAD * NC), dim3(256), 0, stream, kv);
    hipLaunchKernelGGL(chunk_out_mfma,dim3(NBATCH * NHEAD * NC), dim3(256), 0, stream, q, k, vt, kv, o);

    hipLaunchKernelGGL((gemm_bt<true,  false, float>), ggrid, dim3(256), 0, stream,
                       o, Wob, out, (u16*)nullptr, MROWS, DIM, DIM, 1.0f);
}

// Round 4
// 646.485 us; speedup vs baseline: 1.3361x; 1.0802x over previous
//
#include <hip/hip_runtime.h>

typedef unsigned short u16;
typedef __attribute__((ext_vector_type(8))) short short8;
typedef __attribute__((ext_vector_type(8))) unsigned short u16x8;
typedef __attribute__((ext_vector_type(4))) unsigned short u16x4;
typedef __attribute__((ext_vector_type(2))) unsigned short u16x2;
typedef __attribute__((ext_vector_type(4))) float f32x4;

#define NBATCH 2
#define SEQ    4096
#define DIM    2048
#define NHEAD  16
#define HD     128
#define CH     64
#define NC     64           /* SEQ / CH */
#define MROWS  8192         /* NBATCH * SEQ */

__device__ __forceinline__ float b2f(u16 u) {
    unsigned x = ((unsigned)u) << 16;
    return __builtin_bit_cast(float, x);
}
__device__ __forceinline__ u16 f2b(float f) {
    unsigned u = __builtin_bit_cast(unsigned, f);
    u += 0x7fffu + ((u >> 16) & 1u);
    return (u16)(u >> 16);
}

__device__ __forceinline__ void gload_lds16(const u16* g, u16* l) {
    __builtin_amdgcn_global_load_lds(
        (const __attribute__((address_space(1))) void*)g,
        (__attribute__((address_space(3))) void*)l, 16, 0, 0);
}

// ---------------------------------------------------------------------------
// f32 -> bf16 cast (8 elements/thread). n8 = element count / 8.
// ---------------------------------------------------------------------------
__global__ __launch_bounds__(256) void cast_f32_bf16(
    const float* __restrict__ in, u16* __restrict__ out, long n8)
{
    long i = (long)blockIdx.x * 256 + threadIdx.x;
    if (i >= n8) return;
    f32x4 a = ((const f32x4*)in)[2 * i];
    f32x4 b = ((const f32x4*)in)[2 * i + 1];
    u16x8 o;
#pragma unroll
    for (int j = 0; j < 4; j++) { o[j] = f2b(a[j]); o[4 + j] = f2b(b[j]); }
    ((u16x8*)out)[i] = o;
}

// all four weight matrices in one dispatch; seg uniform per block (2048 blk/seg)
__global__ __launch_bounds__(256) void cast_w4(
    const float* __restrict__ w0, const float* __restrict__ w1,
    const float* __restrict__ w2, const float* __restrict__ w3,
    u16* __restrict__ o0, u16* __restrict__ o1,
    u16* __restrict__ o2, u16* __restrict__ o3)
{
    const int seg = blockIdx.x >> 11;
    const float* in = seg == 0 ? w0 : seg == 1 ? w1 : seg == 2 ? w2 : w3;
    u16* out = seg == 0 ? o0 : seg == 1 ? o1 : seg == 2 ? o2 : o3;
    long i = (long)(blockIdx.x & 2047) * 256 + threadIdx.x;
    f32x4 a = ((const f32x4*)in)[2 * i];
    f32x4 b = ((const f32x4*)in)[2 * i + 1];
    u16x8 o;
#pragma unroll
    for (int j = 0; j < 4; j++) { o[j] = f2b(a[j]); o[4 + j] = f2b(b[j]); }
    ((u16x8*)out)[i] = o;
}

// ---------------------------------------------------------------------------
// Shared GEMM tile machinery: C[m,n] = sum_k A[m,k]*B[n,k], 128x128 tile,
// BK=32, 256 thr = 4 waves (2x2 of 64x64), mfma 16x16x32, XOR-swizzled LDS.
// ---------------------------------------------------------------------------
#define BM 128
#define BN 128
#define BK 32

struct GemmCtx {
    int wave, lane, wr, wc, m16, quad;
    int idx0, idx1, r0, k0, r1, k1, fslot;
};

__device__ __forceinline__ GemmCtx gemm_ctx() {
    GemmCtx c;
    const int tid = threadIdx.x;
    c.wave = tid >> 6; c.lane = tid & 63;
    c.wr = c.wave >> 1; c.wc = c.wave & 1;
    c.m16 = c.lane & 15; c.quad = c.lane >> 4;
    c.idx0 = c.wave * 64 + c.lane;
    c.idx1 = c.idx0 + 256;
    c.r0 = c.idx0 >> 2; c.k0 = ((c.idx0 & 3) ^ (c.r0 & 3)) * 8;
    c.r1 = c.idx1 >> 2; c.k1 = ((c.idx1 & 3) ^ (c.r1 & 3)) * 8;
    c.fslot = (c.quad ^ (c.m16 & 3)) * 8;
    return c;
}

// K-loop over K with fixed lda=ldb=DIM
__device__ __forceinline__ void gemm_kloop(
    const GemmCtx& c, const u16* Ab, const u16* Bb, int K,
    u16* As, u16* Bs, f32x4 (&acc)[4][4])
{
    for (int kt = 0; kt < K; kt += BK) {
        if (kt) __syncthreads();
        gload_lds16(Ab + (long)c.r0 * K + kt + c.k0, &As[c.idx0 * 8]);
        gload_lds16(Ab + (long)c.r1 * K + kt + c.k1, &As[c.idx1 * 8]);
        gload_lds16(Bb + (long)c.r0 * K + kt + c.k0, &Bs[c.idx0 * 8]);
        gload_lds16(Bb + (long)c.r1 * K + kt + c.k1, &Bs[c.idx1 * 8]);
        __syncthreads();

        short8 af[4], bf[4];
#pragma unroll
        for (int t = 0; t < 4; t++)
            af[t] = *(const short8*)&As[(c.wr * 64 + t * 16 + c.m16) * BK + c.fslot];
#pragma unroll
        for (int t = 0; t < 4; t++)
            bf[t] = *(const short8*)&Bs[(c.wc * 64 + t * 16 + c.m16) * BK + c.fslot];
#pragma unroll
        for (int i = 0; i < 4; i++)
#pragma unroll
            for (int j = 0; j < 4; j++)
                acc[i][j] = __builtin_amdgcn_mfma_f32_16x16x32_bf16(
                    af[i], bf[j], acc[i][j], 0, 0, 0);
    }
}

// ---------------------------------------------------------------------------
// Fused QKV projection: grid (MROWS/BM, 48). w = y/16 selects weight.
//   w=0: q normal (scaled). w=1: k normal + kt transposed. w=2: vt transposed.
// Transposed layout: Ct[(b*DIM + n)*SEQ + t], token-contiguous per head-col.
// ---------------------------------------------------------------------------
__global__ __launch_bounds__(256) void gemm_qkv(
    const u16* __restrict__ A,
    const u16* __restrict__ Wqb, const u16* __restrict__ Wkb, const u16* __restrict__ Wvb,
    u16* __restrict__ q, u16* __restrict__ k, u16* __restrict__ kt,
    u16* __restrict__ vt, float qscale)
{
    __shared__ __align__(16) u16 As[BM * BK];
    __shared__ __align__(16) u16 Bs[BN * BK];
    const GemmCtx c = gemm_ctx();

    const int w = blockIdx.y >> 4;
    const long row0 = (long)blockIdx.x * BM;
    const long col0 = (long)(blockIdx.y & 15) * BN;
    const u16* Bw = w == 0 ? Wqb : w == 1 ? Wkb : Wvb;

    f32x4 acc[4][4];
#pragma unroll
    for (int i = 0; i < 4; i++)
#pragma unroll
        for (int j = 0; j < 4; j++) {
            f32x4 z = {0.f, 0.f, 0.f, 0.f};
            acc[i][j] = z;
        }

    gemm_kloop(c, A + row0 * DIM, Bw + col0 * DIM, DIM, As, Bs, acc);

    const float scale = (w == 0) ? qscale : 1.0f;
#pragma unroll
    for (int i = 0; i < 4; i++) {
        const long grow0 = row0 + c.wr * 64 + i * 16 + c.quad * 4;
#pragma unroll
        for (int j = 0; j < 4; j++) {
            const long gcol = col0 + c.wc * 64 + j * 16 + c.m16;
            u16x4 p;
#pragma unroll
            for (int r = 0; r < 4; r++) p[r] = f2b(acc[i][j][r] * scale);
            if (w == 0) {
#pragma unroll
                for (int r = 0; r < 4; r++) q[(grow0 + r) * DIM + gcol] = p[r];
            } else {
                const long b = grow0 >> 12;            // batch (SEQ=4096 rows)
                const long t0 = grow0 & (SEQ - 1);
                u16* Ct = (w == 1) ? kt : vt;
                *(u16x4*)(Ct + (b * DIM + gcol) * SEQ + t0) = p;
                if (w == 1) {
#pragma unroll
                    for (int r = 0; r < 4; r++) k[(grow0 + r) * DIM + gcol] = p[r];
                }
            }
        }
    }
}

// ---------------------------------------------------------------------------
// Output GEMM: out[m][n] = sum_k o[m][k] * Wo[n][k], f32 out.
// ---------------------------------------------------------------------------
__global__ __launch_bounds__(256) void gemm_out(
    const u16* __restrict__ A, const u16* __restrict__ Bw, float* __restrict__ C)
{
    __shared__ __align__(16) u16 As[BM * BK];
    __shared__ __align__(16) u16 Bs[BN * BK];
    const GemmCtx c = gemm_ctx();
    const long row0 = (long)blockIdx.x * BM;
    const long col0 = (long)blockIdx.y * BN;

    f32x4 acc[4][4];
#pragma unroll
    for (int i = 0; i < 4; i++)
#pragma unroll
        for (int j = 0; j < 4; j++) {
            f32x4 z = {0.f, 0.f, 0.f, 0.f};
            acc[i][j] = z;
        }

    gemm_kloop(c, A + row0 * DIM, Bw + col0 * DIM, DIM, As, Bs, acc);

#pragma unroll
    for (int i = 0; i < 4; i++) {
        const long grow0 = row0 + c.wr * 64 + i * 16 + c.quad * 4;
#pragma unroll
        for (int j = 0; j < 4; j++) {
            const long gcol = col0 + c.wc * 64 + j * 16 + c.m16;
#pragma unroll
            for (int r = 0; r < 4; r++)
                C[(grow0 + r) * DIM + gcol] = acc[i][j][r];
        }
    }
}

// ---------------------------------------------------------------------------
// chunk_kv (MFMA): kvT[blk][e][d] = sum_t Vt[e][t] Kt[d][t]; frags from global.
// ---------------------------------------------------------------------------
__global__ __launch_bounds__(256) void chunk_kv_mfma(
    const u16* __restrict__ Vt, const u16* __restrict__ Kt, u16* __restrict__ KV)
{
    const int tid = threadIdx.x, blk = blockIdx.x;
    const int c = blk & (NC - 1), bh = blk >> 6;
    const int wave = tid >> 6, lane = tid & 63;
    const int wr = wave >> 1, wc = wave & 1;
    const int m16 = lane & 15, quad = lane >> 4;
    const u16* vb = Vt + (long)bh * HD * SEQ + c * CH;
    const u16* kb = Kt + (long)bh * HD * SEQ + c * CH;

    f32x4 acc[4][4];
#pragma unroll
    for (int i = 0; i < 4; i++)
#pragma unroll
        for (int j = 0; j < 4; j++) {
            f32x4 z = {0.f, 0.f, 0.f, 0.f};
            acc[i][j] = z;
        }

#pragma unroll
    for (int tk = 0; tk < 2; tk++) {
        short8 af[4], bf[4];
#pragma unroll
        for (int t = 0; t < 4; t++)
            af[t] = *(const short8*)(vb + (long)(wr * 64 + t * 16 + m16) * SEQ + tk * 32 + quad * 8);
#pragma unroll
        for (int t = 0; t < 4; t++)
            bf[t] = *(const short8*)(kb + (long)(wc * 64 + t * 16 + m16) * SEQ + tk * 32 + quad * 8);
#pragma unroll
        for (int i = 0; i < 4; i++)
#pragma unroll
            for (int j = 0; j < 4; j++)
                acc[i][j] = __builtin_amdgcn_mfma_f32_16x16x32_bf16(
                    af[i], bf[j], acc[i][j], 0, 0, 0);
    }

    u16* outp = KV + (long)blk * (HD * HD);
#pragma unroll
    for (int i = 0; i < 4; i++)
#pragma unroll
        for (int j = 0; j < 4; j++)
#pragma unroll
            for (int r = 0; r < 4; r++)
                outp[(wr * 64 + i * 16 + quad * 4 + r) * HD + wc * 64 + j * 16 + m16]
                    = f2b(acc[i][j][r]);
}

// ---------------------------------------------------------------------------
// exclusive prefix over chunks, in place, u16x2 vectorized.
// grid: 32 bh * 32 sub = 1024 blocks, 256 thr; thread owns 2 elems.
// ---------------------------------------------------------------------------
__global__ __launch_bounds__(256) void kv_prefix(u16* __restrict__ KV)
{
    const int bh  = blockIdx.x >> 5;
    const int sub = blockIdx.x & 31;
    const long base = (long)bh * NC * (HD * HD) + (sub * 256 + threadIdx.x) * 2;
    float s0 = 0.f, s1 = 0.f;
#pragma unroll 4
    for (int c = 0; c < NC; c++) {
        u16* p = KV + base + (long)c * (HD * HD);
        u16x2 v = *(u16x2*)p;
        u16x2 w; w[0] = f2b(s0); w[1] = f2b(s1);
        *(u16x2*)p = w;
        s0 += b2f(v[0]); s1 += b2f(v[1]);
    }
}

// ---------------------------------------------------------------------------
// chunk_out (MFMA): O = mask(Q K^T) V + Q S  per 64-token chunk.
// ---------------------------------------------------------------------------
#define AMP 72   /* padded LDS stride */

__global__ __launch_bounds__(256) void chunk_out_mfma(
    const u16* __restrict__ Q, const u16* __restrict__ Kn,
    const u16* __restrict__ Vt, const u16* __restrict__ Sb, u16* __restrict__ O)
{
    __shared__ __align__(16) u16 Am[CH * AMP];   // 9216 B

    const int tid = threadIdx.x, blk = blockIdx.x;
    const int c = blk & (NC - 1), bh = blk >> 6;
    const int h = bh & (NHEAD - 1), b = bh >> 4;
    const long rowbase = (long)b * SEQ + (long)c * CH;
    const int wave = tid >> 6, lane = tid & 63;   // wave = m-tile
    const int m16 = lane & 15, quad = lane >> 4;

    const u16* qrow = Q  + (rowbase + wave * 16 + m16) * DIM + h * HD;
    const u16* krow = Kn + rowbase * DIM + h * HD;

    short8 qa[4];
#pragma unroll
    for (int dk = 0; dk < 4; dk++)
        qa[dk] = *(const short8*)(qrow + dk * 32 + quad * 8);

    // phase 1: A = mask(Q K^T) -> LDS (A-op layout)
    f32x4 acc1[4];
#pragma unroll
    for (int jt = 0; jt < 4; jt++) {
        f32x4 z = {0.f, 0.f, 0.f, 0.f};
        acc1[jt] = z;
    }
#pragma unroll
    for (int dk = 0; dk < 4; dk++)
#pragma unroll
        for (int jt = 0; jt < 4; jt++) {
            short8 bb = *(const short8*)(krow + (long)(jt * 16 + m16) * DIM + dk * 32 + quad * 8);
            acc1[jt] = __builtin_amdgcn_mfma_f32_16x16x32_bf16(qa[dk], bb, acc1[jt], 0, 0, 0);
        }
    const int mbase = wave * 16 + quad * 4;
#pragma unroll
    for (int jt = 0; jt < 4; jt++) {
        const int j = jt * 16 + m16;
#pragma unroll
        for (int r = 0; r < 4; r++) {
            float v = (j <= mbase + r) ? acc1[jt][r] : 0.f;
            Am[(mbase + r) * AMP + j] = f2b(v);
        }
    }

    // phase 2: acc = Q * S (S^T rows d-contiguous)
    f32x4 acc[8];
#pragma unroll
    for (int et = 0; et < 8; et++) {
        f32x4 z = {0.f, 0.f, 0.f, 0.f};
        acc[et] = z;
    }
    const u16* Sg = Sb + (long)blk * (HD * HD);
#pragma unroll
    for (int dk = 0; dk < 4; dk++)
#pragma unroll
        for (int et = 0; et < 8; et++) {
            short8 sb = *(const short8*)(Sg + (et * 16 + m16) * HD + dk * 32 + quad * 8);
            acc[et] = __builtin_amdgcn_mfma_f32_16x16x32_bf16(qa[dk], sb, acc[et], 0, 0, 0);
        }

    // phase 3: acc += A * V (A from own-wave LDS rows, V^T t-contiguous)
    const u16* vb = Vt + (long)bh * HD * SEQ + c * CH;
#pragma unroll
    for (int tk = 0; tk < 2; tk++) {
        short8 a = *(const short8*)&Am[(wave * 16 + m16) * AMP + tk * 32 + quad * 8];
#pragma unroll
        for (int et = 0; et < 8; et++) {
            short8 vbf = *(const short8*)(vb + (long)(et * 16 + m16) * SEQ + tk * 32 + quad * 8);
            acc[et] = __builtin_amdgcn_mfma_f32_16x16x32_bf16(a, vbf, acc[et], 0, 0, 0);
        }
    }

#pragma unroll
    for (int et = 0; et < 8; et++) {
        const int e = et * 16 + m16;
#pragma unroll
        for (int r = 0; r < 4; r++) {
            const int m = wave * 16 + quad * 4 + r;
            O[(rowbase + m) * DIM + h * HD + e] = f2b(acc[et][r]);
        }
    }
}

// ---------------------------------------------------------------------------
extern "C" void kernel_launch(void* const* d_in, const int* in_sizes, int n_in,
                              void* d_out, int out_size, void* d_ws, size_t ws_size,
                              hipStream_t stream)
{
    (void)in_sizes; (void)n_in; (void)out_size; (void)ws_size;
    const float* x  = (const float*)d_in[0];
    const float* Wq = (const float*)d_in[1];
    const float* Wk = (const float*)d_in[2];
    const float* Wv = (const float*)d_in[3];
    const float* Wo = (const float*)d_in[4];
    float* out = (float*)d_out;

    const long NE = (long)MROWS * DIM;        // 16,777,216 elements
    const long WE = (long)DIM * DIM;          //  4,194,304 elements
    u16* xb  = (u16*)d_ws;                    // 33.5 MB
    u16* Wqb = xb  + NE;
    u16* Wkb = Wqb + WE;
    u16* Wvb = Wkb + WE;
    u16* Wob = Wvb + WE;
    u16* q   = Wob + WE;                      // 33.5 MB each
    u16* k   = q + NE;
    u16* vt  = k + NE;                        // transposed [b,h,e][t]
    u16* kv  = vt + NE;                       // 67.1 MB (kvT per chunk)
    u16* o   = xb;                            // alias: xb dead after projections
    u16* kt  = (u16*)d_out;                   // scratch in d_out (overwritten later)

    hipLaunchKernelGGL(cast_f32_bf16, dim3(8192), dim3(256), 0, stream, x, xb, NE / 8);
    hipLaunchKernelGGL(cast_w4, dim3(8192), dim3(256), 0, stream,
                       Wq, Wk, Wv, Wo, Wqb, Wkb, Wvb, Wob);

    const float qscale = 0.08838834764831845f;  // HD^-0.5

    hipLaunchKernelGGL(gemm_qkv, dim3(MROWS / BM, 48), dim3(256), 0, stream,
                       xb, Wqb, Wkb, Wvb, q, k, kt, vt, qscale);

    hipLaunchKernelGGL(chunk_kv_mfma, dim3(NBATCH * NHEAD * NC), dim3(256), 0, stream, vt, kt, kv);
    hipLaunchKernelGGL(kv_prefix,     dim3(1024),                dim3(256), 0, stream, kv);
    hipLaunchKernelGGL(chunk_out_mfma,dim3(NBATCH * NHEAD * NC), dim3(256), 0, stream, q, k, vt, kv, o);

    hipLaunchKernelGGL(gemm_out, dim3(MROWS / BM, DIM / BN), dim3(256), 0, stream, o, Wob, out);
}

// Round 5
// 617.784 us; speedup vs baseline: 1.3982x; 1.0465x over previous
//
#include <hip/hip_runtime.h>

typedef unsigned short u16;
typedef __attribute__((ext_vector_type(8))) short short8;
typedef __attribute__((ext_vector_type(8))) unsigned short u16x8;
typedef __attribute__((ext_vector_type(4))) unsigned short u16x4;
typedef __attribute__((ext_vector_type(2))) unsigned short u16x2;
typedef __attribute__((ext_vector_type(4))) float f32x4;

#define NBATCH 2
#define SEQ    4096
#define DIM    2048
#define NHEAD  16
#define HD     128
#define CH     64
#define NC     64           /* SEQ / CH */
#define MROWS  8192         /* NBATCH * SEQ */

__device__ __forceinline__ float b2f(u16 u) {
    unsigned x = ((unsigned)u) << 16;
    return __builtin_bit_cast(float, x);
}
__device__ __forceinline__ u16 f2b(float f) {
    unsigned u = __builtin_bit_cast(unsigned, f);
    u += 0x7fffu + ((u >> 16) & 1u);
    return (u16)(u >> 16);
}

__device__ __forceinline__ void gload_lds16(const u16* g, u16* l) {
    __builtin_amdgcn_global_load_lds(
        (const __attribute__((address_space(1))) void*)g,
        (__attribute__((address_space(3))) void*)l, 16, 0, 0);
}

// ---------------------------------------------------------------------------
// Unified f32->bf16 cast for x + 4 weights in ONE dispatch.
// Blocks 0..8191: x (NE elems). Then 2048 blocks per weight.
// ---------------------------------------------------------------------------
__global__ __launch_bounds__(256) void cast_all(
    const float* __restrict__ x,
    const float* __restrict__ w0, const float* __restrict__ w1,
    const float* __restrict__ w2, const float* __restrict__ w3,
    u16* __restrict__ xo,
    u16* __restrict__ o0, u16* __restrict__ o1,
    u16* __restrict__ o2, u16* __restrict__ o3)
{
    const int blk = blockIdx.x;
    const float* in;
    u16* out;
    long i;
    if (blk < 8192) {
        in = x; out = xo;
        i = (long)blk * 256 + threadIdx.x;
    } else {
        const int seg = (blk - 8192) >> 11;
        in  = seg == 0 ? w0 : seg == 1 ? w1 : seg == 2 ? w2 : w3;
        out = seg == 0 ? o0 : seg == 1 ? o1 : seg == 2 ? o2 : o3;
        i = (long)((blk - 8192) & 2047) * 256 + threadIdx.x;
    }
    f32x4 a = ((const f32x4*)in)[2 * i];
    f32x4 b = ((const f32x4*)in)[2 * i + 1];
    u16x8 o;
#pragma unroll
    for (int j = 0; j < 4; j++) { o[j] = f2b(a[j]); o[4 + j] = f2b(b[j]); }
    ((u16x8*)out)[i] = o;
}

// ---------------------------------------------------------------------------
// Shared GEMM tile machinery: C[m,n] = sum_k A[m,k]*B[n,k], 128x128 tile,
// BK=64 (32 KB LDS, halves barrier count vs BK=32), 256 thr = 4 waves
// (2x2 of 64x64), mfma 16x16x32, 8-slot XOR-swizzled LDS.
// LDS write addr is lane-linear (global_load_lds wave-uniform-base rule);
// the XOR swizzle is applied to the GLOBAL k-offset fetched into each slot.
// ---------------------------------------------------------------------------
#define BM 128
#define BN 128
#define BK 64

struct GemmCtx {
    int wave, lane, wr, wc, m16, quad;
    int row[4], koff[4], ldso[4];   // staging: 4 16B segments per matrix
    int fs0, fs1;                   // fragment slots for kgroup 0/1
};

__device__ __forceinline__ GemmCtx gemm_ctx() {
    GemmCtx c;
    const int tid = threadIdx.x;
    c.wave = tid >> 6; c.lane = tid & 63;
    c.wr = c.wave >> 1; c.wc = c.wave & 1;
    c.m16 = c.lane & 15; c.quad = c.lane >> 4;
#pragma unroll
    for (int i = 0; i < 4; i++) {
        const int idx = c.wave * 64 + c.lane + 256 * i;
        const int row = idx >> 3, ps = idx & 7;
        c.row[i]  = row;
        c.koff[i] = (ps ^ (row & 7)) * 8;
        c.ldso[i] = idx * 8;
    }
    c.fs0 = ((0 + c.quad) ^ (c.m16 & 7)) * 8;
    c.fs1 = ((4 + c.quad) ^ (c.m16 & 7)) * 8;
    return c;
}

__device__ __forceinline__ void gemm_kloop(
    const GemmCtx& c, const u16* Ab, const u16* Bb, int K,
    u16* As, u16* Bs, f32x4 (&acc)[4][4])
{
    for (int kt = 0; kt < K; kt += BK) {
        if (kt) __syncthreads();
#pragma unroll
        for (int i = 0; i < 4; i++)
            gload_lds16(Ab + (long)c.row[i] * K + kt + c.koff[i], &As[c.ldso[i]]);
#pragma unroll
        for (int i = 0; i < 4; i++)
            gload_lds16(Bb + (long)c.row[i] * K + kt + c.koff[i], &Bs[c.ldso[i]]);
        __syncthreads();

#pragma unroll
        for (int kg = 0; kg < 2; kg++) {
            const int fs = kg ? c.fs1 : c.fs0;
            short8 af[4], bf[4];
#pragma unroll
            for (int t = 0; t < 4; t++)
                af[t] = *(const short8*)&As[(c.wr * 64 + t * 16 + c.m16) * BK + fs];
#pragma unroll
            for (int t = 0; t < 4; t++)
                bf[t] = *(const short8*)&Bs[(c.wc * 64 + t * 16 + c.m16) * BK + fs];
#pragma unroll
            for (int i = 0; i < 4; i++)
#pragma unroll
                for (int j = 0; j < 4; j++)
                    acc[i][j] = __builtin_amdgcn_mfma_f32_16x16x32_bf16(
                        af[i], bf[j], acc[i][j], 0, 0, 0);
        }
    }
}

// ---------------------------------------------------------------------------
// Fused QKV projection: grid (MROWS/BM, 48). w = y/16 selects weight.
//   w=0: q normal (scaled). w=1: k normal + kt transposed. w=2: vt transposed.
// Transposed layout: Ct[(b*DIM + n)*SEQ + t], token-contiguous per head-col.
// ---------------------------------------------------------------------------
__global__ __launch_bounds__(256) void gemm_qkv(
    const u16* __restrict__ A,
    const u16* __restrict__ Wqb, const u16* __restrict__ Wkb, const u16* __restrict__ Wvb,
    u16* __restrict__ q, u16* __restrict__ k, u16* __restrict__ kt,
    u16* __restrict__ vt, float qscale)
{
    __shared__ __align__(16) u16 As[BM * BK];
    __shared__ __align__(16) u16 Bs[BN * BK];
    const GemmCtx c = gemm_ctx();

    const int w = blockIdx.y >> 4;
    const long row0 = (long)blockIdx.x * BM;
    const long col0 = (long)(blockIdx.y & 15) * BN;
    const u16* Bw = w == 0 ? Wqb : w == 1 ? Wkb : Wvb;

    f32x4 acc[4][4];
#pragma unroll
    for (int i = 0; i < 4; i++)
#pragma unroll
        for (int j = 0; j < 4; j++) {
            f32x4 z = {0.f, 0.f, 0.f, 0.f};
            acc[i][j] = z;
        }

    gemm_kloop(c, A + row0 * DIM, Bw + col0 * DIM, DIM, As, Bs, acc);

    const float scale = (w == 0) ? qscale : 1.0f;
#pragma unroll
    for (int i = 0; i < 4; i++) {
        const long grow0 = row0 + c.wr * 64 + i * 16 + c.quad * 4;
#pragma unroll
        for (int j = 0; j < 4; j++) {
            const long gcol = col0 + c.wc * 64 + j * 16 + c.m16;
            u16x4 p;
#pragma unroll
            for (int r = 0; r < 4; r++) p[r] = f2b(acc[i][j][r] * scale);
            if (w == 0) {
#pragma unroll
                for (int r = 0; r < 4; r++) q[(grow0 + r) * DIM + gcol] = p[r];
            } else {
                const long b = grow0 >> 12;            // batch (SEQ=4096 rows)
                const long t0 = grow0 & (SEQ - 1);
                u16* Ct = (w == 1) ? kt : vt;
                *(u16x4*)(Ct + (b * DIM + gcol) * SEQ + t0) = p;
                if (w == 1) {
#pragma unroll
                    for (int r = 0; r < 4; r++) k[(grow0 + r) * DIM + gcol] = p[r];
                }
            }
        }
    }
}

// ---------------------------------------------------------------------------
// Output GEMM: out[m][n] = sum_k o[m][k] * Wo[n][k], f32 out.
// ---------------------------------------------------------------------------
__global__ __launch_bounds__(256) void gemm_out(
    const u16* __restrict__ A, const u16* __restrict__ Bw, float* __restrict__ C)
{
    __shared__ __align__(16) u16 As[BM * BK];
    __shared__ __align__(16) u16 Bs[BN * BK];
    const GemmCtx c = gemm_ctx();
    const long row0 = (long)blockIdx.x * BM;
    const long col0 = (long)blockIdx.y * BN;

    f32x4 acc[4][4];
#pragma unroll
    for (int i = 0; i < 4; i++)
#pragma unroll
        for (int j = 0; j < 4; j++) {
            f32x4 z = {0.f, 0.f, 0.f, 0.f};
            acc[i][j] = z;
        }

    gemm_kloop(c, A + row0 * DIM, Bw + col0 * DIM, DIM, As, Bs, acc);

#pragma unroll
    for (int i = 0; i < 4; i++) {
        const long grow0 = row0 + c.wr * 64 + i * 16 + c.quad * 4;
#pragma unroll
        for (int j = 0; j < 4; j++) {
            const long gcol = col0 + c.wc * 64 + j * 16 + c.m16;
#pragma unroll
            for (int r = 0; r < 4; r++)
                C[(grow0 + r) * DIM + gcol] = acc[i][j][r];
        }
    }
}

// ---------------------------------------------------------------------------
// chunk_kv (MFMA): kvT[blk][e][d] = sum_t Vt[e][t] Kt[d][t]; frags from global.
// ---------------------------------------------------------------------------
__global__ __launch_bounds__(256) void chunk_kv_mfma(
    const u16* __restrict__ Vt, const u16* __restrict__ Kt, u16* __restrict__ KV)
{
    const int tid = threadIdx.x, blk = blockIdx.x;
    const int c = blk & (NC - 1), bh = blk >> 6;
    const int wave = tid >> 6, lane = tid & 63;
    const int wr = wave >> 1, wc = wave & 1;
    const int m16 = lane & 15, quad = lane >> 4;
    const u16* vb = Vt + (long)bh * HD * SEQ + c * CH;
    const u16* kb = Kt + (long)bh * HD * SEQ + c * CH;

    f32x4 acc[4][4];
#pragma unroll
    for (int i = 0; i < 4; i++)
#pragma unroll
        for (int j = 0; j < 4; j++) {
            f32x4 z = {0.f, 0.f, 0.f, 0.f};
            acc[i][j] = z;
        }

#pragma unroll
    for (int tk = 0; tk < 2; tk++) {
        short8 af[4], bf[4];
#pragma unroll
        for (int t = 0; t < 4; t++)
            af[t] = *(const short8*)(vb + (long)(wr * 64 + t * 16 + m16) * SEQ + tk * 32 + quad * 8);
#pragma unroll
        for (int t = 0; t < 4; t++)
            bf[t] = *(const short8*)(kb + (long)(wc * 64 + t * 16 + m16) * SEQ + tk * 32 + quad * 8);
#pragma unroll
        for (int i = 0; i < 4; i++)
#pragma unroll
            for (int j = 0; j < 4; j++)
                acc[i][j] = __builtin_amdgcn_mfma_f32_16x16x32_bf16(
                    af[i], bf[j], acc[i][j], 0, 0, 0);
    }

    u16* outp = KV + (long)blk * (HD * HD);
#pragma unroll
    for (int i = 0; i < 4; i++)
#pragma unroll
        for (int j = 0; j < 4; j++)
#pragma unroll
            for (int r = 0; r < 4; r++)
                outp[(wr * 64 + i * 16 + quad * 4 + r) * HD + wc * 64 + j * 16 + m16]
                    = f2b(acc[i][j][r]);
}

// ---------------------------------------------------------------------------
// exclusive prefix over chunks, in place, u16x2 vectorized.
// grid: 32 bh * 32 sub = 1024 blocks, 256 thr; thread owns 2 elems.
// ---------------------------------------------------------------------------
__global__ __launch_bounds__(256) void kv_prefix(u16* __restrict__ KV)
{
    const int bh  = blockIdx.x >> 5;
    const int sub = blockIdx.x & 31;
    const long base = (long)bh * NC * (HD * HD) + (sub * 256 + threadIdx.x) * 2;
    float s0 = 0.f, s1 = 0.f;
#pragma unroll 4
    for (int c = 0; c < NC; c++) {
        u16* p = KV + base + (long)c * (HD * HD);
        u16x2 v = *(u16x2*)p;
        u16x2 w; w[0] = f2b(s0); w[1] = f2b(s1);
        *(u16x2*)p = w;
        s0 += b2f(v[0]); s1 += b2f(v[1]);
    }
}

// ---------------------------------------------------------------------------
// chunk_out (MFMA): O = mask(Q K^T) V + Q S  per 64-token chunk.
// ---------------------------------------------------------------------------
#define AMP 72   /* padded LDS stride */

__global__ __launch_bounds__(256) void chunk_out_mfma(
    const u16* __restrict__ Q, const u16* __restrict__ Kn,
    const u16* __restrict__ Vt, const u16* __restrict__ Sb, u16* __restrict__ O)
{
    __shared__ __align__(16) u16 Am[CH * AMP];   // 9216 B

    const int tid = threadIdx.x, blk = blockIdx.x;
    const int c = blk & (NC - 1), bh = blk >> 6;
    const int h = bh & (NHEAD - 1), b = bh >> 4;
    const long rowbase = (long)b * SEQ + (long)c * CH;
    const int wave = tid >> 6, lane = tid & 63;   // wave = m-tile
    const int m16 = lane & 15, quad = lane >> 4;

    const u16* qrow = Q  + (rowbase + wave * 16 + m16) * DIM + h * HD;
    const u16* krow = Kn + rowbase * DIM + h * HD;

    short8 qa[4];
#pragma unroll
    for (int dk = 0; dk < 4; dk++)
        qa[dk] = *(const short8*)(qrow + dk * 32 + quad * 8);

    // phase 1: A = mask(Q K^T) -> LDS (A-op layout)
    f32x4 acc1[4];
#pragma unroll
    for (int jt = 0; jt < 4; jt++) {
        f32x4 z = {0.f, 0.f, 0.f, 0.f};
        acc1[jt] = z;
    }
#pragma unroll
    for (int dk = 0; dk < 4; dk++)
#pragma unroll
        for (int jt = 0; jt < 4; jt++) {
            short8 bb = *(const short8*)(krow + (long)(jt * 16 + m16) * DIM + dk * 32 + quad * 8);
            acc1[jt] = __builtin_amdgcn_mfma_f32_16x16x32_bf16(qa[dk], bb, acc1[jt], 0, 0, 0);
        }
    const int mbase = wave * 16 + quad * 4;
#pragma unroll
    for (int jt = 0; jt < 4; jt++) {
        const int j = jt * 16 + m16;
#pragma unroll
        for (int r = 0; r < 4; r++) {
            float v = (j <= mbase + r) ? acc1[jt][r] : 0.f;
            Am[(mbase + r) * AMP + j] = f2b(v);
        }
    }

    // phase 2: acc = Q * S (S^T rows d-contiguous)
    f32x4 acc[8];
#pragma unroll
    for (int et = 0; et < 8; et++) {
        f32x4 z = {0.f, 0.f, 0.f, 0.f};
        acc[et] = z;
    }
    const u16* Sg = Sb + (long)blk * (HD * HD);
#pragma unroll
    for (int dk = 0; dk < 4; dk++)
#pragma unroll
        for (int et = 0; et < 8; et++) {
            short8 sb = *(const short8*)(Sg + (et * 16 + m16) * HD + dk * 32 + quad * 8);
            acc[et] = __builtin_amdgcn_mfma_f32_16x16x32_bf16(qa[dk], sb, acc[et], 0, 0, 0);
        }

    // phase 3: acc += A * V (A from own-wave LDS rows, V^T t-contiguous)
    const u16* vb = Vt + (long)bh * HD * SEQ + c * CH;
#pragma unroll
    for (int tk = 0; tk < 2; tk++) {
        short8 a = *(const short8*)&Am[(wave * 16 + m16) * AMP + tk * 32 + quad * 8];
#pragma unroll
        for (int et = 0; et < 8; et++) {
            short8 vbf = *(const short8*)(vb + (long)(et * 16 + m16) * SEQ + tk * 32 + quad * 8);
            acc[et] = __builtin_amdgcn_mfma_f32_16x16x32_bf16(a, vbf, acc[et], 0, 0, 0);
        }
    }

#pragma unroll
    for (int et = 0; et < 8; et++) {
        const int e = et * 16 + m16;
#pragma unroll
        for (int r = 0; r < 4; r++) {
            const int m = wave * 16 + quad * 4 + r;
            O[(rowbase + m) * DIM + h * HD + e] = f2b(acc[et][r]);
        }
    }
}

// ---------------------------------------------------------------------------
extern "C" void kernel_launch(void* const* d_in, const int* in_sizes, int n_in,
                              void* d_out, int out_size, void* d_ws, size_t ws_size,
                              hipStream_t stream)
{
    (void)in_sizes; (void)n_in; (void)out_size; (void)ws_size;
    const float* x  = (const float*)d_in[0];
    const float* Wq = (const float*)d_in[1];
    const float* Wk = (const float*)d_in[2];
    const float* Wv = (const float*)d_in[3];
    const float* Wo = (const float*)d_in[4];
    float* out = (float*)d_out;

    const long NE = (long)MROWS * DIM;        // 16,777,216 elements
    const long WE = (long)DIM * DIM;          //  4,194,304 elements
    u16* xb  = (u16*)d_ws;                    // 33.5 MB
    u16* Wqb = xb  + NE;
    u16* Wkb = Wqb + WE;
    u16* Wvb = Wkb + WE;
    u16* Wob = Wvb + WE;
    u16* q   = Wob + WE;                      // 33.5 MB each
    u16* k   = q + NE;
    u16* vt  = k + NE;                        // transposed [b,h,e][t]
    u16* kv  = vt + NE;                       // 67.1 MB (kvT per chunk)
    u16* o   = xb;                            // alias: xb dead after projections
    u16* kt  = (u16*)d_out;                   // scratch in d_out (overwritten later)

    hipLaunchKernelGGL(cast_all, dim3(16384), dim3(256), 0, stream,
                       x, Wq, Wk, Wv, Wo, xb, Wqb, Wkb, Wvb, Wob);

    const float qscale = 0.08838834764831845f;  // HD^-0.5

    hipLaunchKernelGGL(gemm_qkv, dim3(MROWS / BM, 48), dim3(256), 0, stream,
                       xb, Wqb, Wkb, Wvb, q, k, kt, vt, qscale);

    hipLaunchKernelGGL(chunk_kv_mfma, dim3(NBATCH * NHEAD * NC), dim3(256), 0, stream, vt, kt, kv);
    hipLaunchKernelGGL(kv_prefix,     dim3(1024),                dim3(256), 0, stream, kv);
    hipLaunchKernelGGL(chunk_out_mfma,dim3(NBATCH * NHEAD * NC), dim3(256), 0, stream, q, k, vt, kv, o);

    hipLaunchKernelGGL(gemm_out, dim3(MROWS / BM, DIM / BN), dim3(256), 0, stream, o, Wob, out);
}